// Round 3
// baseline (2240.788 us; speedup 1.0000x reference)
//
#include <hip/hip_runtime.h>

typedef __attribute__((ext_vector_type(4))) float fx4;
typedef __attribute__((ext_vector_type(8))) short s16x8;

#define SEQ   2048
#define DM    1024
#define BSZ   4
#define ROWS  (BSZ*SEQ)   /* 8192 */
#define CHUNK 64
#define NCH   (SEQ/CHUNK) /* 32 */

__device__ __forceinline__ unsigned short f2bf(float f){
  unsigned u = __builtin_bit_cast(unsigned, f);
  u = u + 0x7FFFu + ((u >> 16) & 1u);
  return (unsigned short)(u >> 16);
}

__device__ __forceinline__ float gelu_f(float x){
  float u = 0.7978845608028654f * (x + 0.044715f * x*x*x);
  return 0.5f * x * (1.0f + tanhf(u));
}

__device__ __forceinline__ void gload_lds16(const void* g, void* l){
  __builtin_amdgcn_global_load_lds(
      (__attribute__((address_space(1))) void*)g,
      (__attribute__((address_space(3))) void*)l, 16, 0, 0);
}

// ---------------- transpose fp32 [R][C] -> bf16 [C][R], batched ----------------
__global__ __launch_bounds__(256) void transpose_k(const float* __restrict__ in,
    unsigned short* __restrict__ out, int R, int C, long long ibs, long long obs){
  __shared__ float tile[32][33];
  in  += (long long)blockIdx.z * ibs;
  out += (long long)blockIdx.z * obs;
  int c0 = blockIdx.x*32, r0 = blockIdx.y*32;
  int tx = threadIdx.x, ty = threadIdx.y;
  #pragma unroll
  for (int i=0;i<4;i++)
    tile[ty+8*i][tx] = in[(long long)(r0+ty+8*i)*C + c0+tx];
  __syncthreads();
  #pragma unroll
  for (int i=0;i<4;i++)
    out[(long long)(c0+ty+8*i)*R + r0+tx] = f2bf(tile[tx][ty+8*i]);
}

// ---------------- LayerNorm over D=1024, one block per row ----------------
__global__ __launch_bounds__(256) void ln_rows(const float* __restrict__ x,
    const float* __restrict__ g, const float* __restrict__ b,
    unsigned short* __restrict__ out){
  int row = blockIdx.x, t = threadIdx.x;
  const fx4* xr = (const fx4*)(x + (long long)row*DM);
  fx4 v = xr[t];
  float s  = v[0]+v[1]+v[2]+v[3];
  float s2 = v[0]*v[0]+v[1]*v[1]+v[2]*v[2]+v[3]*v[3];
  #pragma unroll
  for (int o=32;o;o>>=1){ s += __shfl_down(s,o); s2 += __shfl_down(s2,o); }
  __shared__ float red[8];
  int lane = t & 63, wid = t >> 6;
  if (lane==0){ red[wid]=s; red[4+wid]=s2; }
  __syncthreads();
  s  = red[0]+red[1]+red[2]+red[3];
  s2 = red[4]+red[5]+red[6]+red[7];
  float m  = s * (1.0f/DM);
  float rs = rsqrtf(s2*(1.0f/DM) - m*m + 1e-5f);
  const fx4 gv = ((const fx4*)g)[t], bv = ((const fx4*)b)[t];
  ushort4 pk;
  pk.x = f2bf((v[0]-m)*rs*gv[0] + bv[0]);
  pk.y = f2bf((v[1]-m)*rs*gv[1] + bv[1]);
  pk.z = f2bf((v[2]-m)*rs*gv[2] + bv[2]);
  pk.w = f2bf((v[3]-m)*rs*gv[3] + bv[3]);
  *(ushort4*)(out + (long long)row*DM + t*4) = pk;
}

// ---------------- scan pass 1: per-chunk carries ----------------
__global__ __launch_bounds__(256) void scan_carry(const float* __restrict__ P,
    const float* __restrict__ w_row, const float* __restrict__ dcol,
    const float* __restrict__ drow, float* __restrict__ carry){
  int g = blockIdx.x*4 + (threadIdx.x>>6);
  int lane = threadIdx.x & 63;
  int chunk = g & (NCH-1); int bh = g >> 5; int h = bh & 15; int b = bh >> 4;
  float draw = (h<8) ? dcol[h] : drow[h-8];
  float d = powf(fminf(fmaxf(draw,0.9f),1.0f), 0.25f);
  float c = 0.f;
  const float* p = P + ((long long)(b*SEQ + chunk*CHUNK))*DM + h*64 + lane;
  const float* wr = w_row + (h>=8 ? (h-8)*SEQ + chunk*CHUNK : 0);
  #pragma unroll 4
  for (int i=0;i<CHUNK;i++){
    float a = p[(long long)i*DM];
    if (h>=8) a *= wr[i];
    c = fmaf(d, c, a);
  }
  carry[((long long)(bh*64 + lane))*NCH + chunk] = c;
}

// ---------------- scan pass 2: apply carries, emit mix (bf16) ----------------
__global__ __launch_bounds__(256) void scan_final(const float* __restrict__ P,
    const float* __restrict__ w_col, const float* __restrict__ b_col,
    const float* __restrict__ w_row, const float* __restrict__ b_row,
    const float* __restrict__ dcol, const float* __restrict__ drow,
    const float* __restrict__ carry, unsigned short* __restrict__ mix){
  int g = blockIdx.x*4 + (threadIdx.x>>6);
  int lane = threadIdx.x & 63;
  int chunk = g & (NCH-1); int bh = g >> 5; int h = bh & 15; int b = bh >> 4;
  float draw = (h<8) ? dcol[h] : drow[h-8];
  float d = powf(fminf(fmaxf(draw,0.9f),1.0f), 0.25f);
  float dL = d;
  #pragma unroll
  for (int i=0;i<6;i++) dL *= dL;        // d^64
  const float* cr = carry + ((long long)(bh*64 + lane))*NCH;
  float c = 0.f;
  for (int j=0;j<chunk;j++) c = fmaf(dL, c, cr[j]);   // carry-in
  const float* p = P + ((long long)(b*SEQ + chunk*CHUNK))*DM + h*64 + lane;
  unsigned short* mo = mix + ((long long)(b*SEQ + chunk*CHUNK))*DM + h*64 + lane;
  int t0 = chunk*CHUNK;
  #pragma unroll 4
  for (int i=0;i<CHUNK;i++){
    int t = t0 + i;
    float a = p[(long long)i*DM];
    float o;
    if (h<8){
      c = fmaf(d, c, a);
      o = w_col[h*SEQ + t]*c + b_col[h*SEQ + t];
    } else {
      a *= w_row[(h-8)*SEQ + t];
      c = fmaf(d, c, a);
      o = c + b_row[(h-8)*SEQ + t];
    }
    mo[(long long)i*DM] = f2bf(o);
  }
}

// ---------------- GEMM: A[M][K] bf16 x Bt[N][K] bf16 -> out [M][N] ----------------
// EPI 0: outf = acc + bias[n]                  (fp32)
// EPI 1: outf = acc + bias[n] + res[idx]       (fp32)
// EPI 2: outb = bf16(gelu(acc + bias[n]))      (bf16)
// 128x128 tile, BK=64, 4 waves. Hoisted addressing; LDS-coalesced epilogue;
// XCD-aware block swizzle; setprio around MFMA cluster.
// NOTE: no min-waves in launch_bounds — (256,3) in round 2 capped VGPRs at 60
// and spilled acc to scratch (FETCH 57MB->1.3GB, 742us). Registers > occupancy here.
template<int EPI>
__global__ __launch_bounds__(256) void gemm_bt(const unsigned short* __restrict__ A,
    const unsigned short* __restrict__ Bt, int K, int N,
    const float* __restrict__ bias, const float* __restrict__ res,
    float* __restrict__ outf, unsigned short* __restrict__ outb){
  __shared__ __align__(16) unsigned short lds[16384];   // As 128x64, Bs 128x64 (32KB)
  const int tid = threadIdx.x;
  const int l = tid & 63;
  const int w = tid >> 6;
  const int wr = w >> 1, wc = w & 1;

  // XCD-aware swizzle (gridDim.x == 64 for all our GEMMs; nwg % 8 == 0)
  unsigned lin = blockIdx.y * 64u + blockIdx.x;
  unsigned nwg = 64u * gridDim.y;
  unsigned swz = (lin & 7u) * (nwg >> 3) + (lin >> 3);
  const long long row0 = (long long)(swz & 63u) * 128;
  const long long col0 = (long long)(swz >> 6)  * 128;

  fx4 acc[4][4] = {};

  // ---- hoisted staging addresses (pointer-increment per K-step) ----
  const unsigned short* gA[4];
  const unsigned short* gB[4];
  int lslot[4];
  #pragma unroll
  for (int i=0;i<4;i++){
    int slot = w*256 + i*64 + l;
    int r = slot >> 3;
    int qs = slot & 7;
    int c = (qs ^ (r & 7)) << 3;     // inverse swizzle on global source
    gA[i] = A  + (row0 + r)*(long long)K + c;
    gB[i] = Bt + (col0 + r)*(long long)K + c;
    lslot[i] = slot*8;
  }
  // ---- hoisted LDS fragment offsets ----
  int aoff[2][4], boff[2][4];
  #pragma unroll
  for (int kk=0;kk<2;kk++){
    #pragma unroll
    for (int m=0;m<4;m++){
      int r  = wr*64 + m*16 + (l&15);
      int q  = (kk*4 + (l>>4)) ^ (r&7);
      aoff[kk][m] = r*64 + q*8;
      int r2 = wc*64 + m*16 + (l&15);
      int q2 = (kk*4 + (l>>4)) ^ (r2&7);
      boff[kk][m] = 8192 + r2*64 + q2*8;
    }
  }

  const int nsteps = K >> 6;
  for (int s = 0; s < nsteps; ++s){
    #pragma unroll
    for (int i=0;i<4;i++){
      gload_lds16(gA[i], &lds[lslot[i]]);
      gload_lds16(gB[i], &lds[8192 + lslot[i]]);
      gA[i] += 64; gB[i] += 64;
    }
    __syncthreads();
    __builtin_amdgcn_s_setprio(1);
    #pragma unroll
    for (int kk=0;kk<2;kk++){
      s16x8 af[4], bfr[4];
      #pragma unroll
      for (int m=0;m<4;m++) af[m]  = *(const s16x8*)&lds[aoff[kk][m]];
      #pragma unroll
      for (int n=0;n<4;n++) bfr[n] = *(const s16x8*)&lds[boff[kk][n]];
      #pragma unroll
      for (int m=0;m<4;m++)
        #pragma unroll
        for (int n=0;n<4;n++)
          acc[m][n] = __builtin_amdgcn_mfma_f32_16x16x32_bf16(af[m], bfr[n], acc[m][n], 0, 0, 0);
    }
    __builtin_amdgcn_s_setprio(0);
    __syncthreads();
  }

  // ---- LDS-staged coalesced epilogue: 32-row groups, full-line stores ----
  float* lf = (float*)lds;              // [32][132] fp32 = 16.9KB
  const int lg = l >> 4, lc = l & 15;
  #pragma unroll 1
  for (int g=0; g<4; ++g){
    if (wr == (g>>1)){
      int mbase = (g&1)*2;
      #pragma unroll
      for (int mm=0; mm<2; ++mm){
        int m = mbase + mm;
        int lrow = mm*16 + lg*4;        // 0..28
        #pragma unroll
        for (int n=0;n<4;n++){
          int col = wc*64 + n*16 + lc;
          #pragma unroll
          for (int rg=0;rg<4;rg++)
            lf[(lrow+rg)*132 + col] = acc[m][n][rg];
        }
      }
    }
    __syncthreads();
    #pragma unroll
    for (int j=0;j<4;j++){
      int flat = j*256 + tid;           // 0..1023
      int lrow = flat >> 5, c4 = flat & 31;
      long long grow = row0 + g*32 + lrow;
      long long gcol = col0 + c4*4;
      fx4 v = *(fx4*)&lf[lrow*132 + c4*4];
      fx4 bv = *(const fx4*)&bias[gcol];
      v = v + bv;
      long long idx = grow*(long long)N + gcol;
      if constexpr (EPI==0){
        *(fx4*)&outf[idx] = v;
      } else if constexpr (EPI==1){
        fx4 rv = *(const fx4*)&res[idx];
        v = v + rv;
        *(fx4*)&outf[idx] = v;
      } else {
        ushort4 pk;
        pk.x = f2bf(gelu_f(v[0]));
        pk.y = f2bf(gelu_f(v[1]));
        pk.z = f2bf(gelu_f(v[2]));
        pk.w = f2bf(gelu_f(v[3]));
        *(ushort4*)&outb[idx] = pk;
      }
    }
    __syncthreads();
  }
}

// ---------------- host ----------------
extern "C" void kernel_launch(void* const* d_in, const int* in_sizes, int n_in,
                              void* d_out, int out_size, void* d_ws, size_t ws_size,
                              hipStream_t stream){
  const float* x    = (const float*)d_in[0];
  const float* g1   = (const float*)d_in[1];
  const float* b1   = (const float*)d_in[2];
  const float* g2   = (const float*)d_in[3];
  const float* b2   = (const float*)d_in[4];
  const float* Wp   = (const float*)d_in[5];
  const float* bp   = (const float*)d_in[6];
  const float* Wo   = (const float*)d_in[7];
  const float* bo   = (const float*)d_in[8];
  const float* w_col= (const float*)d_in[9];
  const float* b_col= (const float*)d_in[10];
  const float* w_row= (const float*)d_in[11];
  const float* b_row= (const float*)d_in[12];
  const float* dcol = (const float*)d_in[13];
  const float* drow = (const float*)d_in[14];
  const float* W1   = (const float*)d_in[15];
  const float* c1   = (const float*)d_in[16];
  const float* W2   = (const float*)d_in[17];
  const float* c2   = (const float*)d_in[18];
  float* out = (float*)d_out;

  char* ws = (char*)d_ws;
  const size_t MB = 1024*1024;
  if (ws_size < 101*MB) return;
  unsigned short* Wpt = (unsigned short*)(ws + 0);
  unsigned short* Wot = (unsigned short*)(ws + 2*MB);
  unsigned short* W1t = (unsigned short*)(ws + 4*MB);
  unsigned short* W2t = (unsigned short*)(ws + 12*MB);
  unsigned short* h   = (unsigned short*)(ws + 20*MB);   // later reused as yln
  float*          P   = (float*)(ws + 36*MB);
  unsigned short* mix = (unsigned short*)(ws + 68*MB);
  float*          carry=(float*)(ws + 84*MB);
  unsigned short* U   = (unsigned short*)(ws + 36*MB);   // overlaps P/mix/carry (dead by then)
  unsigned short* yln = h;

  dim3 tb(32,8);
  transpose_k<<<dim3(2,32,16),  tb, 0, stream>>>(Wp, Wpt, 1024,   64, 65536LL, 65536LL);
  transpose_k<<<dim3(32,32,1),  tb, 0, stream>>>(Wo, Wot, 1024, 1024, 0LL, 0LL);
  transpose_k<<<dim3(128,32,1), tb, 0, stream>>>(W1, W1t, 1024, 4096, 0LL, 0LL);
  transpose_k<<<dim3(32,128,1), tb, 0, stream>>>(W2, W2t, 4096, 1024, 0LL, 0LL);

  ln_rows<<<dim3(ROWS), dim3(256), 0, stream>>>(x, g1, b1, h);
  gemm_bt<0><<<dim3(64,8),  dim3(256), 0, stream>>>(h,   Wpt, 1024, 1024, bp, nullptr, P, nullptr);
  scan_carry<<<dim3(512), dim3(256), 0, stream>>>(P, w_row, dcol, drow, carry);
  scan_final<<<dim3(512), dim3(256), 0, stream>>>(P, w_col, b_col, w_row, b_row, dcol, drow, carry, mix);
  gemm_bt<1><<<dim3(64,8),  dim3(256), 0, stream>>>(mix, Wot, 1024, 1024, bo, x, out, nullptr);
  ln_rows<<<dim3(ROWS), dim3(256), 0, stream>>>(out, g2, b2, yln);
  gemm_bt<2><<<dim3(64,32), dim3(256), 0, stream>>>(yln, W1t, 1024, 4096, c1, nullptr, nullptr, U);
  gemm_bt<1><<<dim3(64,8),  dim3(256), 0, stream>>>(U,   W2t, 4096, 1024, c2, out, out, nullptr);
}

// Round 4
// 365.149 us; speedup vs baseline: 6.1366x; 6.1366x over previous
//
#include <hip/hip_runtime.h>

typedef __attribute__((ext_vector_type(4))) float fx4;
typedef __attribute__((ext_vector_type(8))) short s16x8;

#define SEQ   2048
#define DM    1024
#define BSZ   4
#define ROWS  (BSZ*SEQ)   /* 8192 */
#define CHUNK 64
#define NCH   (SEQ/CHUNK) /* 32 */

__device__ __forceinline__ unsigned short f2bf(float f){
  unsigned u = __builtin_bit_cast(unsigned, f);
  u = u + 0x7FFFu + ((u >> 16) & 1u);
  return (unsigned short)(u >> 16);
}

__device__ __forceinline__ float gelu_f(float x){
  float u = 0.7978845608028654f * (x + 0.044715f * x*x*x);
  return 0.5f * x * (1.0f + tanhf(u));
}

__device__ __forceinline__ void gload_lds16(const void* g, void* l){
  __builtin_amdgcn_global_load_lds(
      (__attribute__((address_space(1))) void*)g,
      (__attribute__((address_space(3))) void*)l, 16, 0, 0);
}

// ---------------- transpose fp32 [R][C] -> bf16 [C][R], batched ----------------
__global__ __launch_bounds__(256) void transpose_k(const float* __restrict__ in,
    unsigned short* __restrict__ out, int R, int C, long long ibs, long long obs){
  __shared__ float tile[32][33];
  in  += (long long)blockIdx.z * ibs;
  out += (long long)blockIdx.z * obs;
  int c0 = blockIdx.x*32, r0 = blockIdx.y*32;
  int tx = threadIdx.x, ty = threadIdx.y;
  #pragma unroll
  for (int i=0;i<4;i++)
    tile[ty+8*i][tx] = in[(long long)(r0+ty+8*i)*C + c0+tx];
  __syncthreads();
  #pragma unroll
  for (int i=0;i<4;i++)
    out[(long long)(c0+ty+8*i)*R + r0+tx] = f2bf(tile[tx][ty+8*i]);
}

// ---------------- LayerNorm over D=1024, one block per row ----------------
__global__ __launch_bounds__(256) void ln_rows(const float* __restrict__ x,
    const float* __restrict__ g, const float* __restrict__ b,
    unsigned short* __restrict__ out){
  int row = blockIdx.x, t = threadIdx.x;
  const fx4* xr = (const fx4*)(x + (long long)row*DM);
  fx4 v = xr[t];
  float s  = v[0]+v[1]+v[2]+v[3];
  float s2 = v[0]*v[0]+v[1]*v[1]+v[2]*v[2]+v[3]*v[3];
  #pragma unroll
  for (int o=32;o;o>>=1){ s += __shfl_down(s,o); s2 += __shfl_down(s2,o); }
  __shared__ float red[8];
  int lane = t & 63, wid = t >> 6;
  if (lane==0){ red[wid]=s; red[4+wid]=s2; }
  __syncthreads();
  s  = red[0]+red[1]+red[2]+red[3];
  s2 = red[4]+red[5]+red[6]+red[7];
  float m  = s * (1.0f/DM);
  float rs = rsqrtf(s2*(1.0f/DM) - m*m + 1e-5f);
  const fx4 gv = ((const fx4*)g)[t], bv = ((const fx4*)b)[t];
  ushort4 pk;
  pk.x = f2bf((v[0]-m)*rs*gv[0] + bv[0]);
  pk.y = f2bf((v[1]-m)*rs*gv[1] + bv[1]);
  pk.z = f2bf((v[2]-m)*rs*gv[2] + bv[2]);
  pk.w = f2bf((v[3]-m)*rs*gv[3] + bv[3]);
  *(ushort4*)(out + (long long)row*DM + t*4) = pk;
}

// ---------------- scan pass 1: per-chunk carries ----------------
__global__ __launch_bounds__(256) void scan_carry(const float* __restrict__ P,
    const float* __restrict__ w_row, const float* __restrict__ dcol,
    const float* __restrict__ drow, float* __restrict__ carry){
  int g = blockIdx.x*4 + (threadIdx.x>>6);
  int lane = threadIdx.x & 63;
  int chunk = g & (NCH-1); int bh = g >> 5; int h = bh & 15; int b = bh >> 4;
  float draw = (h<8) ? dcol[h] : drow[h-8];
  float d = powf(fminf(fmaxf(draw,0.9f),1.0f), 0.25f);
  float c = 0.f;
  const float* p = P + ((long long)(b*SEQ + chunk*CHUNK))*DM + h*64 + lane;
  const float* wr = w_row + (h>=8 ? (h-8)*SEQ + chunk*CHUNK : 0);
  #pragma unroll 4
  for (int i=0;i<CHUNK;i++){
    float a = p[(long long)i*DM];
    if (h>=8) a *= wr[i];
    c = fmaf(d, c, a);
  }
  carry[((long long)(bh*64 + lane))*NCH + chunk] = c;
}

// ---------------- scan pass 2: apply carries, emit mix (bf16) ----------------
__global__ __launch_bounds__(256) void scan_final(const float* __restrict__ P,
    const float* __restrict__ w_col, const float* __restrict__ b_col,
    const float* __restrict__ w_row, const float* __restrict__ b_row,
    const float* __restrict__ dcol, const float* __restrict__ drow,
    const float* __restrict__ carry, unsigned short* __restrict__ mix){
  int g = blockIdx.x*4 + (threadIdx.x>>6);
  int lane = threadIdx.x & 63;
  int chunk = g & (NCH-1); int bh = g >> 5; int h = bh & 15; int b = bh >> 4;
  float draw = (h<8) ? dcol[h] : drow[h-8];
  float d = powf(fminf(fmaxf(draw,0.9f),1.0f), 0.25f);
  float dL = d;
  #pragma unroll
  for (int i=0;i<6;i++) dL *= dL;        // d^64
  const float* cr = carry + ((long long)(bh*64 + lane))*NCH;
  float c = 0.f;
  for (int j=0;j<chunk;j++) c = fmaf(dL, c, cr[j]);   // carry-in
  const float* p = P + ((long long)(b*SEQ + chunk*CHUNK))*DM + h*64 + lane;
  unsigned short* mo = mix + ((long long)(b*SEQ + chunk*CHUNK))*DM + h*64 + lane;
  int t0 = chunk*CHUNK;
  #pragma unroll 4
  for (int i=0;i<CHUNK;i++){
    int t = t0 + i;
    float a = p[(long long)i*DM];
    float o;
    if (h<8){
      c = fmaf(d, c, a);
      o = w_col[h*SEQ + t]*c + b_col[h*SEQ + t];
    } else {
      a *= w_row[(h-8)*SEQ + t];
      c = fmaf(d, c, a);
      o = c + b_row[(h-8)*SEQ + t];
    }
    mo[(long long)i*DM] = f2bf(o);
  }
}

// ---------------- GEMM: A[M][K] bf16 x Bt[N][K] bf16 -> out [M][N] ----------------
// EPI 0: outf = acc + bias[n]                  (fp32)
// EPI 1: outf = acc + bias[n] + res[idx]       (fp32)
// EPI 2: outb = bf16(gelu(acc + bias[n]))      (bf16)
// 128x128 tile, BK=64, 4 waves.
// HISTORY: (256,3) capped VGPR->spill (round 2); "#pragma unroll 1" on the
// epilogue g-loop made acc runtime-indexed -> WHOLE acc demoted to scratch,
// 2.9GB writes (round 3, rule #20). Epilogue must be FULLY unrolled.
template<int EPI>
__global__ __launch_bounds__(256) void gemm_bt(const unsigned short* __restrict__ A,
    const unsigned short* __restrict__ Bt, int K, int N,
    const float* __restrict__ bias, const float* __restrict__ res,
    float* __restrict__ outf, unsigned short* __restrict__ outb){
  __shared__ __align__(16) unsigned short lds[16384];   // As 128x64, Bs 128x64 (32KB)
  const int tid = threadIdx.x;
  const int l = tid & 63;
  const int w = tid >> 6;
  const int wr = w >> 1, wc = w & 1;

  // XCD-aware swizzle (gridDim.x == 64 for all our GEMMs; nwg % 8 == 0)
  unsigned lin = blockIdx.y * 64u + blockIdx.x;
  unsigned nwg = 64u * gridDim.y;
  unsigned swz = (lin & 7u) * (nwg >> 3) + (lin >> 3);
  const long long row0 = (long long)(swz & 63u) * 128;
  const long long col0 = (long long)(swz >> 6)  * 128;

  fx4 acc[4][4] = {};

  // ---- hoisted staging addresses (pointer-increment per K-step) ----
  const unsigned short* gA[4];
  const unsigned short* gB[4];
  int lslot[4];
  #pragma unroll
  for (int i=0;i<4;i++){
    int slot = w*256 + i*64 + l;
    int r = slot >> 3;
    int qs = slot & 7;
    int c = (qs ^ (r & 7)) << 3;     // inverse swizzle on global source
    gA[i] = A  + (row0 + r)*(long long)K + c;
    gB[i] = Bt + (col0 + r)*(long long)K + c;
    lslot[i] = slot*8;
  }
  // ---- hoisted LDS fragment offsets ----
  int aoff[2][4], boff[2][4];
  #pragma unroll
  for (int kk=0;kk<2;kk++){
    #pragma unroll
    for (int m=0;m<4;m++){
      int r  = wr*64 + m*16 + (l&15);
      int q  = (kk*4 + (l>>4)) ^ (r&7);
      aoff[kk][m] = r*64 + q*8;
      int r2 = wc*64 + m*16 + (l&15);
      int q2 = (kk*4 + (l>>4)) ^ (r2&7);
      boff[kk][m] = 8192 + r2*64 + q2*8;
    }
  }

  const int nsteps = K >> 6;
  for (int s = 0; s < nsteps; ++s){
    #pragma unroll
    for (int i=0;i<4;i++){
      gload_lds16(gA[i], &lds[lslot[i]]);
      gload_lds16(gB[i], &lds[8192 + lslot[i]]);
      gA[i] += 64; gB[i] += 64;
    }
    __syncthreads();
    __builtin_amdgcn_s_setprio(1);
    #pragma unroll
    for (int kk=0;kk<2;kk++){
      s16x8 af[4], bfr[4];
      #pragma unroll
      for (int m=0;m<4;m++) af[m]  = *(const s16x8*)&lds[aoff[kk][m]];
      #pragma unroll
      for (int n=0;n<4;n++) bfr[n] = *(const s16x8*)&lds[boff[kk][n]];
      #pragma unroll
      for (int m=0;m<4;m++)
        #pragma unroll
        for (int n=0;n<4;n++)
          acc[m][n] = __builtin_amdgcn_mfma_f32_16x16x32_bf16(af[m], bfr[n], acc[m][n], 0, 0, 0);
    }
    __builtin_amdgcn_s_setprio(0);
    __syncthreads();
  }

  // ---- LDS-staged coalesced epilogue: 32-row groups, full-line stores ----
  // FULLY unrolled so every acc[][] index is compile-time (rule #20).
  float* lf = (float*)lds;              // [32][132] fp32 = 16.9KB
  const int lg = l >> 4, lc = l & 15;
  #pragma unroll
  for (int g=0; g<4; ++g){
    if (wr == (g>>1)){
      #pragma unroll
      for (int mm=0; mm<2; ++mm){
        const int m = (g&1)*2 + mm;     // compile-time per unrolled copy
        int lrow = mm*16 + lg*4;        // 0..28
        #pragma unroll
        for (int n=0;n<4;n++){
          int col = wc*64 + n*16 + lc;
          #pragma unroll
          for (int rg=0;rg<4;rg++)
            lf[(lrow+rg)*132 + col] = acc[m][n][rg];
        }
      }
    }
    __syncthreads();
    #pragma unroll
    for (int j=0;j<4;j++){
      int flat = j*256 + tid;           // 0..1023
      int lrow = flat >> 5, c4 = flat & 31;
      long long grow = row0 + g*32 + lrow;
      long long gcol = col0 + c4*4;
      fx4 v = *(fx4*)&lf[lrow*132 + c4*4];
      fx4 bv = *(const fx4*)&bias[gcol];
      v = v + bv;
      long long idx = grow*(long long)N + gcol;
      if constexpr (EPI==0){
        *(fx4*)&outf[idx] = v;
      } else if constexpr (EPI==1){
        fx4 rv = *(const fx4*)&res[idx];
        v = v + rv;
        *(fx4*)&outf[idx] = v;
      } else {
        ushort4 pk;
        pk.x = f2bf(gelu_f(v[0]));
        pk.y = f2bf(gelu_f(v[1]));
        pk.z = f2bf(gelu_f(v[2]));
        pk.w = f2bf(gelu_f(v[3]));
        *(ushort4*)&outb[idx] = pk;
      }
    }
    __syncthreads();
  }
}

// ---------------- host ----------------
extern "C" void kernel_launch(void* const* d_in, const int* in_sizes, int n_in,
                              void* d_out, int out_size, void* d_ws, size_t ws_size,
                              hipStream_t stream){
  const float* x    = (const float*)d_in[0];
  const float* g1   = (const float*)d_in[1];
  const float* b1   = (const float*)d_in[2];
  const float* g2   = (const float*)d_in[3];
  const float* b2   = (const float*)d_in[4];
  const float* Wp   = (const float*)d_in[5];
  const float* bp   = (const float*)d_in[6];
  const float* Wo   = (const float*)d_in[7];
  const float* bo   = (const float*)d_in[8];
  const float* w_col= (const float*)d_in[9];
  const float* b_col= (const float*)d_in[10];
  const float* w_row= (const float*)d_in[11];
  const float* b_row= (const float*)d_in[12];
  const float* dcol = (const float*)d_in[13];
  const float* drow = (const float*)d_in[14];
  const float* W1   = (const float*)d_in[15];
  const float* c1   = (const float*)d_in[16];
  const float* W2   = (const float*)d_in[17];
  const float* c2   = (const float*)d_in[18];
  float* out = (float*)d_out;

  char* ws = (char*)d_ws;
  const size_t MB = 1024*1024;
  if (ws_size < 101*MB) return;
  unsigned short* Wpt = (unsigned short*)(ws + 0);
  unsigned short* Wot = (unsigned short*)(ws + 2*MB);
  unsigned short* W1t = (unsigned short*)(ws + 4*MB);
  unsigned short* W2t = (unsigned short*)(ws + 12*MB);
  unsigned short* h   = (unsigned short*)(ws + 20*MB);   // later reused as yln
  float*          P   = (float*)(ws + 36*MB);
  unsigned short* mix = (unsigned short*)(ws + 68*MB);
  float*          carry=(float*)(ws + 84*MB);
  unsigned short* U   = (unsigned short*)(ws + 36*MB);   // overlaps P/mix/carry (dead by then)
  unsigned short* yln = h;

  dim3 tb(32,8);
  transpose_k<<<dim3(2,32,16),  tb, 0, stream>>>(Wp, Wpt, 1024,   64, 65536LL, 65536LL);
  transpose_k<<<dim3(32,32,1),  tb, 0, stream>>>(Wo, Wot, 1024, 1024, 0LL, 0LL);
  transpose_k<<<dim3(128,32,1), tb, 0, stream>>>(W1, W1t, 1024, 4096, 0LL, 0LL);
  transpose_k<<<dim3(32,128,1), tb, 0, stream>>>(W2, W2t, 4096, 1024, 0LL, 0LL);

  ln_rows<<<dim3(ROWS), dim3(256), 0, stream>>>(x, g1, b1, h);
  gemm_bt<0><<<dim3(64,8),  dim3(256), 0, stream>>>(h,   Wpt, 1024, 1024, bp, nullptr, P, nullptr);
  scan_carry<<<dim3(512), dim3(256), 0, stream>>>(P, w_row, dcol, drow, carry);
  scan_final<<<dim3(512), dim3(256), 0, stream>>>(P, w_col, b_col, w_row, b_row, dcol, drow, carry, mix);
  gemm_bt<1><<<dim3(64,8),  dim3(256), 0, stream>>>(mix, Wot, 1024, 1024, bo, x, out, nullptr);
  ln_rows<<<dim3(ROWS), dim3(256), 0, stream>>>(out, g2, b2, yln);
  gemm_bt<2><<<dim3(64,32), dim3(256), 0, stream>>>(yln, W1t, 1024, 4096, c1, nullptr, nullptr, U);
  gemm_bt<1><<<dim3(64,8),  dim3(256), 0, stream>>>(U,   W2t, 4096, 1024, c2, out, out, nullptr);
}

// Round 5
// 308.360 us; speedup vs baseline: 7.2668x; 1.1842x over previous
//
#include <hip/hip_runtime.h>

typedef __attribute__((ext_vector_type(4))) float fx4;
typedef __attribute__((ext_vector_type(8))) short s16x8;

#define SEQ   2048
#define DM    1024
#define BSZ   4
#define ROWS  (BSZ*SEQ)   /* 8192 */
#define CHUNK 64
#define NCH   (SEQ/CHUNK) /* 32 */

__device__ __forceinline__ unsigned short f2bf(float f){
  unsigned u = __builtin_bit_cast(unsigned, f);
  u = u + 0x7FFFu + ((u >> 16) & 1u);
  return (unsigned short)(u >> 16);
}

// fast tanh-gelu: 0.5x(1+tanh(u)) == x*sigmoid(2u); __expf -> v_exp_f32
__device__ __forceinline__ float gelu_f(float x){
  float u = 0.7978845608028654f * (x + 0.044715f * x*x*x);
  return x / (1.0f + __expf(-2.0f*u));
}

__device__ __forceinline__ void gload_lds16(const void* g, void* l){
  __builtin_amdgcn_global_load_lds(
      (__attribute__((address_space(1))) void*)g,
      (__attribute__((address_space(3))) void*)l, 16, 0, 0);
}

// ---------------- transpose fp32 [R][C] -> bf16 [C][R], batched ----------------
__global__ __launch_bounds__(256) void transpose_k(const float* __restrict__ in,
    unsigned short* __restrict__ out, int R, int C, long long ibs, long long obs){
  __shared__ float tile[32][33];
  in  += (long long)blockIdx.z * ibs;
  out += (long long)blockIdx.z * obs;
  int c0 = blockIdx.x*32, r0 = blockIdx.y*32;
  int tx = threadIdx.x, ty = threadIdx.y;
  #pragma unroll
  for (int i=0;i<4;i++)
    tile[ty+8*i][tx] = in[(long long)(r0+ty+8*i)*C + c0+tx];
  __syncthreads();
  #pragma unroll
  for (int i=0;i<4;i++)
    out[(long long)(c0+ty+8*i)*R + r0+tx] = f2bf(tile[tx][ty+8*i]);
}

// ---------------- LayerNorm over D=1024, one block per row ----------------
__global__ __launch_bounds__(256) void ln_rows(const float* __restrict__ x,
    const float* __restrict__ g, const float* __restrict__ b,
    unsigned short* __restrict__ out){
  int row = blockIdx.x, t = threadIdx.x;
  const fx4* xr = (const fx4*)(x + (long long)row*DM);
  fx4 v = xr[t];
  float s  = v[0]+v[1]+v[2]+v[3];
  float s2 = v[0]*v[0]+v[1]*v[1]+v[2]*v[2]+v[3]*v[3];
  #pragma unroll
  for (int o=32;o;o>>=1){ s += __shfl_down(s,o); s2 += __shfl_down(s2,o); }
  __shared__ float red[8];
  int lane = t & 63, wid = t >> 6;
  if (lane==0){ red[wid]=s; red[4+wid]=s2; }
  __syncthreads();
  s  = red[0]+red[1]+red[2]+red[3];
  s2 = red[4]+red[5]+red[6]+red[7];
  float m  = s * (1.0f/DM);
  float rs = rsqrtf(s2*(1.0f/DM) - m*m + 1e-5f);
  const fx4 gv = ((const fx4*)g)[t], bv = ((const fx4*)b)[t];
  ushort4 pk;
  pk.x = f2bf((v[0]-m)*rs*gv[0] + bv[0]);
  pk.y = f2bf((v[1]-m)*rs*gv[1] + bv[1]);
  pk.z = f2bf((v[2]-m)*rs*gv[2] + bv[2]);
  pk.w = f2bf((v[3]-m)*rs*gv[3] + bv[3]);
  *(ushort4*)(out + (long long)row*DM + t*4) = pk;
}

// ---------------- scan pass 1: per-chunk carries ----------------
__global__ __launch_bounds__(256) void scan_carry(const float* __restrict__ P,
    const float* __restrict__ w_row, const float* __restrict__ dcol,
    const float* __restrict__ drow, float* __restrict__ carry){
  int g = blockIdx.x*4 + (threadIdx.x>>6);
  int lane = threadIdx.x & 63;
  int chunk = g & (NCH-1); int bh = g >> 5; int h = bh & 15; int b = bh >> 4;
  float draw = (h<8) ? dcol[h] : drow[h-8];
  float d = powf(fminf(fmaxf(draw,0.9f),1.0f), 0.25f);
  float c = 0.f;
  const float* p = P + ((long long)(b*SEQ + chunk*CHUNK))*DM + h*64 + lane;
  const float* wr = w_row + (h>=8 ? (h-8)*SEQ + chunk*CHUNK : 0);
  #pragma unroll 4
  for (int i=0;i<CHUNK;i++){
    float a = p[(long long)i*DM];
    if (h>=8) a *= wr[i];
    c = fmaf(d, c, a);
  }
  carry[((long long)(bh*64 + lane))*NCH + chunk] = c;
}

// ---------------- scan pass 2: apply carries, emit mix (bf16) ----------------
__global__ __launch_bounds__(256) void scan_final(const float* __restrict__ P,
    const float* __restrict__ w_col, const float* __restrict__ b_col,
    const float* __restrict__ w_row, const float* __restrict__ b_row,
    const float* __restrict__ dcol, const float* __restrict__ drow,
    const float* __restrict__ carry, unsigned short* __restrict__ mix){
  int g = blockIdx.x*4 + (threadIdx.x>>6);
  int lane = threadIdx.x & 63;
  int chunk = g & (NCH-1); int bh = g >> 5; int h = bh & 15; int b = bh >> 4;
  float draw = (h<8) ? dcol[h] : drow[h-8];
  float d = powf(fminf(fmaxf(draw,0.9f),1.0f), 0.25f);
  float dL = d;
  #pragma unroll
  for (int i=0;i<6;i++) dL *= dL;        // d^64
  const float* cr = carry + ((long long)(bh*64 + lane))*NCH;
  float c = 0.f;
  for (int j=0;j<chunk;j++) c = fmaf(dL, c, cr[j]);   // carry-in
  const float* p = P + ((long long)(b*SEQ + chunk*CHUNK))*DM + h*64 + lane;
  unsigned short* mo = mix + ((long long)(b*SEQ + chunk*CHUNK))*DM + h*64 + lane;
  int t0 = chunk*CHUNK;
  #pragma unroll 4
  for (int i=0;i<CHUNK;i++){
    int t = t0 + i;
    float a = p[(long long)i*DM];
    float o;
    if (h<8){
      c = fmaf(d, c, a);
      o = w_col[h*SEQ + t]*c + b_col[h*SEQ + t];
    } else {
      a *= w_row[(h-8)*SEQ + t];
      c = fmaf(d, c, a);
      o = c + b_row[(h-8)*SEQ + t];
    }
    mo[(long long)i*DM] = f2bf(o);
  }
}

// ---------------- GEMM: A[M][K] bf16 x Bt[N][K] bf16 -> out [M][N] ----------------
// EPI 0: outf = acc + bias[n]                  (fp32)
// EPI 1: outf = acc + bias[n] + res[idx]       (fp32)
// EPI 2: outb = bf16(gelu(acc + bias[n]))      (bf16)
// 128x128 tile, BK=64, 4 waves, 2-PHASE double-buffered LDS (stage next tile
// before compute; one __syncthreads per tile). Natural block mapping: with
// gridDim.x=64, XCD i statically owns rows r==i (mod 8) -> 2MB A-panel stays
// L2-resident (round-4 chunked swizzle broke this: FETCH 57->266MB).
// HISTORY: (256,3) VGPR cap -> spill (r2); runtime-indexed acc -> scratch (r3).
template<int EPI, int K>
__global__ __launch_bounds__(256) void gemm_bt(const unsigned short* __restrict__ A,
    const unsigned short* __restrict__ Bt, int N,
    const float* __restrict__ bias, const float* __restrict__ res,
    float* __restrict__ outf, unsigned short* __restrict__ outb){
  __shared__ __align__(16) unsigned short lds[32768];   // 2 x (As 128x64 + Bs 128x64) = 64KB
  const int tid = threadIdx.x;
  const int l = tid & 63;
  const int w = tid >> 6;
  const int wr = w >> 1, wc = w & 1;

  const long long row0 = (long long)blockIdx.x * 128;
  const long long col0 = (long long)blockIdx.y * 128;

  fx4 acc[4][4] = {};

  // ---- hoisted staging addresses (pointer-increment per K-step) ----
  const unsigned short* gA[4];
  const unsigned short* gB[4];
  int lslot[4];
  #pragma unroll
  for (int i=0;i<4;i++){
    int slot = w*256 + i*64 + l;
    int r = slot >> 3;
    int qs = slot & 7;
    int c = (qs ^ (r & 7)) << 3;     // inverse swizzle on global source
    gA[i] = A  + (row0 + r)*(long long)K + c;
    gB[i] = Bt + (col0 + r)*(long long)K + c;
    lslot[i] = slot*8;
  }
  // ---- hoisted LDS fragment offsets ----
  int aoff[2][4], boff[2][4];
  #pragma unroll
  for (int kk=0;kk<2;kk++){
    #pragma unroll
    for (int m=0;m<4;m++){
      int r  = wr*64 + m*16 + (l&15);
      int q  = (kk*4 + (l>>4)) ^ (r&7);
      aoff[kk][m] = r*64 + q*8;
      int r2 = wc*64 + m*16 + (l&15);
      int q2 = (kk*4 + (l>>4)) ^ (r2&7);
      boff[kk][m] = 8192 + r2*64 + q2*8;
    }
  }

  constexpr int nsteps = K >> 6;

  // prologue: stage tile 0 into buf 0
  #pragma unroll
  for (int i=0;i<4;i++){
    gload_lds16(gA[i], &lds[lslot[i]]);
    gload_lds16(gB[i], &lds[8192 + lslot[i]]);
    gA[i] += 64; gB[i] += 64;
  }
  __syncthreads();

  int curoff = 0;
  for (int s = 0; s < nsteps-1; ++s){
    int nxt = curoff ^ 16384;
    // issue next tile's loads first (in flight during compute)
    #pragma unroll
    for (int i=0;i<4;i++){
      gload_lds16(gA[i], &lds[nxt + lslot[i]]);
      gload_lds16(gB[i], &lds[nxt + 8192 + lslot[i]]);
      gA[i] += 64; gB[i] += 64;
    }
    // compute current buffer
    __builtin_amdgcn_s_setprio(1);
    #pragma unroll
    for (int kk=0;kk<2;kk++){
      s16x8 af[4], bfr[4];
      #pragma unroll
      for (int m=0;m<4;m++) af[m]  = *(const s16x8*)&lds[curoff + aoff[kk][m]];
      #pragma unroll
      for (int n=0;n<4;n++) bfr[n] = *(const s16x8*)&lds[curoff + boff[kk][n]];
      #pragma unroll
      for (int m=0;m<4;m++)
        #pragma unroll
        for (int n=0;n<4;n++)
          acc[m][n] = __builtin_amdgcn_mfma_f32_16x16x32_bf16(af[m], bfr[n], acc[m][n], 0, 0, 0);
    }
    __builtin_amdgcn_s_setprio(0);
    __syncthreads();     // drains next-tile loads + all lds reads of cur
    curoff = nxt;
  }
  // last tile (no prefetch)
  __builtin_amdgcn_s_setprio(1);
  #pragma unroll
  for (int kk=0;kk<2;kk++){
    s16x8 af[4], bfr[4];
    #pragma unroll
    for (int m=0;m<4;m++) af[m]  = *(const s16x8*)&lds[curoff + aoff[kk][m]];
    #pragma unroll
    for (int n=0;n<4;n++) bfr[n] = *(const s16x8*)&lds[curoff + boff[kk][n]];
    #pragma unroll
    for (int m=0;m<4;m++)
      #pragma unroll
      for (int n=0;n<4;n++)
        acc[m][n] = __builtin_amdgcn_mfma_f32_16x16x32_bf16(af[m], bfr[n], acc[m][n], 0, 0, 0);
  }
  __builtin_amdgcn_s_setprio(0);
  __syncthreads();       // all lds use done before epilogue reuses it

  // ---- LDS-staged coalesced epilogue: 32-row groups, full-line stores ----
  // FULLY unrolled so every acc[][] index is compile-time (rule #20).
  float* lf = (float*)lds;              // [32][132] fp32 = 16.9KB
  const int lg = l >> 4, lc = l & 15;
  #pragma unroll
  for (int g=0; g<4; ++g){
    if (wr == (g>>1)){
      #pragma unroll
      for (int mm=0; mm<2; ++mm){
        const int m = (g&1)*2 + mm;     // compile-time per unrolled copy
        int lrow = mm*16 + lg*4;        // 0..28
        #pragma unroll
        for (int n=0;n<4;n++){
          int col = wc*64 + n*16 + lc;
          #pragma unroll
          for (int rg=0;rg<4;rg++)
            lf[(lrow+rg)*132 + col] = acc[m][n][rg];
        }
      }
    }
    __syncthreads();
    #pragma unroll
    for (int j=0;j<4;j++){
      int flat = j*256 + tid;           // 0..1023
      int lrow = flat >> 5, c4 = flat & 31;
      long long grow = row0 + g*32 + lrow;
      long long gcol = col0 + c4*4;
      fx4 v = *(fx4*)&lf[lrow*132 + c4*4];
      fx4 bv = *(const fx4*)&bias[gcol];
      v = v + bv;
      long long idx = grow*(long long)N + gcol;
      if constexpr (EPI==0){
        *(fx4*)&outf[idx] = v;
      } else if constexpr (EPI==1){
        fx4 rv = *(const fx4*)&res[idx];
        v = v + rv;
        *(fx4*)&outf[idx] = v;
      } else {
        ushort4 pk;
        pk.x = f2bf(gelu_f(v[0]));
        pk.y = f2bf(gelu_f(v[1]));
        pk.z = f2bf(gelu_f(v[2]));
        pk.w = f2bf(gelu_f(v[3]));
        *(ushort4*)&outb[idx] = pk;
      }
    }
    __syncthreads();
  }
}

// ---------------- host ----------------
extern "C" void kernel_launch(void* const* d_in, const int* in_sizes, int n_in,
                              void* d_out, int out_size, void* d_ws, size_t ws_size,
                              hipStream_t stream){
  const float* x    = (const float*)d_in[0];
  const float* g1   = (const float*)d_in[1];
  const float* b1   = (const float*)d_in[2];
  const float* g2   = (const float*)d_in[3];
  const float* b2   = (const float*)d_in[4];
  const float* Wp   = (const float*)d_in[5];
  const float* bp   = (const float*)d_in[6];
  const float* Wo   = (const float*)d_in[7];
  const float* bo   = (const float*)d_in[8];
  const float* w_col= (const float*)d_in[9];
  const float* b_col= (const float*)d_in[10];
  const float* w_row= (const float*)d_in[11];
  const float* b_row= (const float*)d_in[12];
  const float* dcol = (const float*)d_in[13];
  const float* drow = (const float*)d_in[14];
  const float* W1   = (const float*)d_in[15];
  const float* c1   = (const float*)d_in[16];
  const float* W2   = (const float*)d_in[17];
  const float* c2   = (const float*)d_in[18];
  float* out = (float*)d_out;

  char* ws = (char*)d_ws;
  const size_t MB = 1024*1024;
  if (ws_size < 101*MB) return;
  unsigned short* Wpt = (unsigned short*)(ws + 0);
  unsigned short* Wot = (unsigned short*)(ws + 2*MB);
  unsigned short* W1t = (unsigned short*)(ws + 4*MB);
  unsigned short* W2t = (unsigned short*)(ws + 12*MB);
  unsigned short* h   = (unsigned short*)(ws + 20*MB);   // later reused as yln
  float*          P   = (float*)(ws + 36*MB);
  unsigned short* mix = (unsigned short*)(ws + 68*MB);
  float*          carry=(float*)(ws + 84*MB);
  unsigned short* U   = (unsigned short*)(ws + 36*MB);   // overlaps P/mix/carry (dead by then)
  unsigned short* yln = h;

  dim3 tb(32,8);
  transpose_k<<<dim3(2,32,16),  tb, 0, stream>>>(Wp, Wpt, 1024,   64, 65536LL, 65536LL);
  transpose_k<<<dim3(32,32,1),  tb, 0, stream>>>(Wo, Wot, 1024, 1024, 0LL, 0LL);
  transpose_k<<<dim3(128,32,1), tb, 0, stream>>>(W1, W1t, 1024, 4096, 0LL, 0LL);
  transpose_k<<<dim3(32,128,1), tb, 0, stream>>>(W2, W2t, 4096, 1024, 0LL, 0LL);

  ln_rows<<<dim3(ROWS), dim3(256), 0, stream>>>(x, g1, b1, h);
  gemm_bt<0,1024><<<dim3(64,8),  dim3(256), 0, stream>>>(h,   Wpt, 1024, bp, nullptr, P, nullptr);
  scan_carry<<<dim3(512), dim3(256), 0, stream>>>(P, w_row, dcol, drow, carry);
  scan_final<<<dim3(512), dim3(256), 0, stream>>>(P, w_col, b_col, w_row, b_row, dcol, drow, carry, mix);
  gemm_bt<1,1024><<<dim3(64,8),  dim3(256), 0, stream>>>(mix, Wot, 1024, bo, x, out, nullptr);
  ln_rows<<<dim3(ROWS), dim3(256), 0, stream>>>(out, g2, b2, yln);
  gemm_bt<2,1024><<<dim3(64,32), dim3(256), 0, stream>>>(yln, W1t, 4096, c1, nullptr, nullptr, U);
  gemm_bt<1,4096><<<dim3(64,8),  dim3(256), 0, stream>>>(U,   W2t, 1024, c2, out, out, nullptr);
}